// Round 2
// baseline (299.616 us; speedup 1.0000x reference)
//
#include <hip/hip_runtime.h>
#include <cstdint>
#include <cstddef>

// x [8,4096,512] fp32, W_enc [512,512], b_enc [512], code_book [128,512].
// Outputs: q, q, z -> 3 x B*DIM fp32. B = 32768.
//
// Round-N+1: 32x32x16 MFMA (2x FLOPs per LDS byte vs 16x16x32 -> LDS-read
// bound Z phase becomes MFMA-bound). K-outer, zacc[8] f32x16 holds full
// 512-col z row-block. Wave = rtile (w&1, 32 rows) x col-tile parity
// (w>>1: tiles {p,p+2} of each 128-col chunk). X read once via direct
// A-fragment global loads. W/cb tiles double-buffered via global_load_lds,
// stage(next) before compute(cur). S phase swapped: S^T = cb @ z^T so each
// lane owns one z-row x 32 codes -> lane-local argmin.
// LDS tile swizzle: chunk p of row r holds global chunk p ^ (r&3)
// (read pattern: 32 consecutive rows per 32 lanes -> conflict-free).

#define DIM     512
#define NCODES  128

typedef _Float16 half8  __attribute__((ext_vector_type(8)));
typedef _Float16 half4h __attribute__((ext_vector_type(4)));
typedef float    f32x4  __attribute__((ext_vector_type(4)));
typedef float    f32x16 __attribute__((ext_vector_type(16)));

__device__ __forceinline__ void load_lds16(const void* gptr, void* ldsptr) {
    __builtin_amdgcn_global_load_lds(
        (const __attribute__((address_space(1))) uint32_t*)(uintptr_t)gptr,
        (__attribute__((address_space(3))) uint32_t*)(uintptr_t)ldsptr,
        16, 0, 0);
}

__device__ __forceinline__ void split_f32(float v, _Float16& h, _Float16& l) {
    h = (_Float16)v;
    l = (_Float16)(v - (float)h);
}

// ---------------------------------------------------------------------------
// Kernel P: split W (512x512) and cb (128x512) into f16 hi/lo arrays in ws.
// ---------------------------------------------------------------------------
__global__ __launch_bounds__(256) void presplit_kernel(
        const float* __restrict__ W, const float* __restrict__ cb,
        _Float16* __restrict__ Wh, _Float16* __restrict__ Wl,
        _Float16* __restrict__ Ch, _Float16* __restrict__ Cl) {
    const int gid = blockIdx.x * 256 + threadIdx.x;
    const float* src; _Float16 *dh, *dl; size_t e;
    if (gid < 65536) { src = W;  dh = Wh; dl = Wl; e = (size_t)gid * 4; }
    else             { src = cb; dh = Ch; dl = Cl; e = (size_t)(gid - 65536) * 4; }
    float4 v = *(const float4*)&src[e];
    _Float16 h0, h1, h2, h3, l0, l1, l2, l3;
    split_f32(v.x, h0, l0); split_f32(v.y, h1, l1);
    split_f32(v.z, h2, l2); split_f32(v.w, h3, l3);
    *(half4h*)&dh[e] = half4h{h0, h1, h2, h3};
    *(half4h*)&dl[e] = half4h{l0, l1, l2, l3};
}

// ---------------------------------------------------------------------------
// Kernel 0: per-code squared norms (fp32). 16 blocks x 256 thr.
// ---------------------------------------------------------------------------
__global__ void code_norms_kernel(const float* __restrict__ cb,
                                  float* __restrict__ cn) {
    const int tid = threadIdx.x;
    const int g = tid >> 5, l = tid & 31;
    const int code = blockIdx.x * 8 + g;
    const float4* row = (const float4*)(cb + (size_t)code * DIM);
    float s = 0.f;
    #pragma unroll
    for (int i = 0; i < 4; ++i) {
        float4 v = row[l + 32 * i];
        s = fmaf(v.x, v.x, s); s = fmaf(v.y, v.y, s);
        s = fmaf(v.z, v.z, s); s = fmaf(v.w, v.w, s);
    }
    #pragma unroll
    for (int m = 16; m >= 1; m >>= 1) s += __shfl_xor(s, m, 64);
    if (l == 0) cn[code] = s;
}

// ---------------------------------------------------------------------------
// Fused kernel: 512 blocks x 64 rows, 256 thr (4 waves).
// Wave w: rtile = w&1 (rows rtile*32..+31), cpar = w>>1 (col-tiles
// {cpar, cpar+2} of each 128-col chunk => 256 cols/wave).
// 32x32x16 frag layouts: A/B lane l: row/col = l&31, k = (l>>5)*8 + 0..7.
// C/D lane l: col = l&31, row = (reg&3) + 8*(reg>>2) + 4*(l>>5).
// ---------------------------------------------------------------------------
__global__ __launch_bounds__(256, 2) void fused_kernel(
        const float* __restrict__ X, const _Float16* __restrict__ Wh,
        const _Float16* __restrict__ Wl, const _Float16* __restrict__ Ch,
        const _Float16* __restrict__ Cl, const float* __restrict__ cb,
        const float* __restrict__ bias, const float* __restrict__ cn,
        float* __restrict__ Z, float* __restrict__ q1,
        float* __restrict__ q2) {
    __shared__ _Float16 BhS[2][128][32];  // 16 KB (dbuf W tile, reused for cb)
    __shared__ _Float16 BlS[2][128][32];  // 16 KB
    __shared__ _Float16 zhS[64][132];     // 16.5 KB (stride 132: 2-way max)
    __shared__ _Float16 zlS[64][132];     // 16.5 KB
    __shared__ float    biasS[DIM];       // 2 KB
    __shared__ float    cnS[NCODES];
    __shared__ float    wval[4][32];
    __shared__ int      widx[4][32];
    __shared__ int      amin[64];

    const int tid  = threadIdx.x;
    const int lane = tid & 63;
    const int w    = tid >> 6;
    const int rb   = lane & 31;           // frag row/col within tile
    const int hi   = lane >> 5;           // k-half selector within frags
    const int rtile = w & 1;
    const int cpar  = w >> 1;
    const size_t row0 = (size_t)blockIdx.x * 64;
    const int wbase = tid & 192;          // wave-uniform thread base

    biasS[tid] = bias[tid];
    biasS[tid + 256] = bias[tid + 256];
    if (tid < NCODES) cnS[tid] = cn[tid];

    // Stage one 128x32-half tile (h and l) into LDS buffer with swizzle
    // chunk p of row r <- global chunk p ^ (r&3).
    auto stage_tile = [&](const _Float16* __restrict__ srcH,
                          const _Float16* __restrict__ srcL,
                          int buf) {
        #pragma unroll
        for (int i = 0; i < 2; ++i) {
            const int slot = i * 256 + tid;
            const int r = slot >> 2, p = slot & 3;
            const int g = p ^ (r & 3);
            load_lds16(&srcH[(size_t)r * DIM + g * 8],
                       (char*)&BhS[buf][0][0] + (size_t)(i * 256 + wbase) * 16);
            load_lds16(&srcL[(size_t)r * DIM + g * 8],
                       (char*)&BlS[buf][0][0] + (size_t)(i * 256 + wbase) * 16);
        }
    };

    // B/A-frag LDS read offsets: row = ct*32 + rb (64 B/row), chunk byte
    // offset = ((2*kh + hi) ^ (rb&3)) * 16 = ck0 ^ (kh*32).
    const int rb3  = rb & 3;
    const int ck0  = (hi ^ rb3) * 16;
    const int browA = (cpar * 32 + rb) * 64;        // ct = cpar
    const int browB = browA + 64 * 64;              // ct = cpar + 2

    // X A-frag: lane reads row rtile*32+rb, k = k0 + k16 + hi*8 + 0..7.
    const float* xptr = X + (row0 + rtile * 32 + rb) * DIM + hi * 8;

    f32x16 zacc[8] = {};   // [chunk nc * 2 + ci]

    // Prologue: stage (k0=0, nc=0) into buf0; prefetch first A groups.
    stage_tile(Wh, Wl, 0);
    f32x4 a00 = *(const f32x4*)(xptr + 0);
    f32x4 a01 = *(const f32x4*)(xptr + 4);
    f32x4 a10 = *(const f32x4*)(xptr + 16);
    f32x4 a11 = *(const f32x4*)(xptr + 20);
    __syncthreads();

    for (int k0i = 0; k0i < 16; ++k0i) {
        const int k0 = k0i * 32;
        // Split A groups (khalf0 from a00/a01, khalf1 from a10/a11).
        half8 ah0, al0, ah1, al1;
        {
            _Float16 h[8], l[8];
            split_f32(a00[0], h[0], l[0]); split_f32(a00[1], h[1], l[1]);
            split_f32(a00[2], h[2], l[2]); split_f32(a00[3], h[3], l[3]);
            split_f32(a01[0], h[4], l[4]); split_f32(a01[1], h[5], l[5]);
            split_f32(a01[2], h[6], l[6]); split_f32(a01[3], h[7], l[7]);
            ah0 = half8{h[0], h[1], h[2], h[3], h[4], h[5], h[6], h[7]};
            al0 = half8{l[0], l[1], l[2], l[3], l[4], l[5], l[6], l[7]};
            split_f32(a10[0], h[0], l[0]); split_f32(a10[1], h[1], l[1]);
            split_f32(a10[2], h[2], l[2]); split_f32(a10[3], h[3], l[3]);
            split_f32(a11[0], h[4], l[4]); split_f32(a11[1], h[5], l[5]);
            split_f32(a11[2], h[6], l[6]); split_f32(a11[3], h[7], l[7]);
            ah1 = half8{h[0], h[1], h[2], h[3], h[4], h[5], h[6], h[7]};
            al1 = half8{l[0], l[1], l[2], l[3], l[4], l[5], l[6], l[7]};
        }
        // Prefetch next k0's A groups.
        if (k0i < 15) {
            a00 = *(const f32x4*)(xptr + k0 + 32);
            a01 = *(const f32x4*)(xptr + k0 + 36);
            a10 = *(const f32x4*)(xptr + k0 + 48);
            a11 = *(const f32x4*)(xptr + k0 + 52);
        }

        #pragma unroll
        for (int nc = 0; nc < 4; ++nc) {
            const int s = k0i * 4 + nc;
            const int cur = s & 1;
            const int nxt = cur ^ 1;
            // Stage NEXT tile before computing current one.
            if (nc < 3 || k0i < 15) {
                const int ncn = (nc + 1) & 3;
                const int k0n = (nc == 3) ? (k0 + 32) : k0;
                stage_tile(Wh + (size_t)(ncn * 128) * DIM + k0n,
                           Wl + (size_t)(ncn * 128) * DIM + k0n, nxt);
            } else {
                // Last Z sub-step: prefetch first cb tile (nc=0, ks=0).
                stage_tile(Ch, Cl, nxt);
            }
            const char* bhp = (const char*)&BhS[cur][0][0];
            const char* blp = (const char*)&BlS[cur][0][0];
            #pragma unroll
            for (int ci = 0; ci < 2; ++ci) {
                const int brow = ci ? browB : browA;
                f32x16 acc = zacc[nc * 2 + ci];
                {   // khalf 0
                    const int off = brow + ck0;
                    half8 bh = *(const half8*)(bhp + off);
                    half8 bl = *(const half8*)(blp + off);
                    acc = __builtin_amdgcn_mfma_f32_32x32x16_f16(ah0, bh, acc, 0, 0, 0);
                    acc = __builtin_amdgcn_mfma_f32_32x32x16_f16(ah0, bl, acc, 0, 0, 0);
                    acc = __builtin_amdgcn_mfma_f32_32x32x16_f16(al0, bh, acc, 0, 0, 0);
                }
                {   // khalf 1
                    const int off = brow + (ck0 ^ 32);
                    half8 bh = *(const half8*)(bhp + off);
                    half8 bl = *(const half8*)(blp + off);
                    acc = __builtin_amdgcn_mfma_f32_32x32x16_f16(ah1, bh, acc, 0, 0, 0);
                    acc = __builtin_amdgcn_mfma_f32_32x32x16_f16(ah1, bl, acc, 0, 0, 0);
                    acc = __builtin_amdgcn_mfma_f32_32x32x16_f16(al1, bh, acc, 0, 0, 0);
                }
                zacc[nc * 2 + ci] = acc;
            }
            __syncthreads();
        }
    }

    // Tail: per nc chunk, epilogue + S^T accumulation (pipelined cb staging).
    f32x16 Sacc[2] = {};
    #pragma unroll
    for (int nc = 0; nc < 4; ++nc) {
        const int col0 = nc * 128;
        // Epilogue: +bias, store z to global, split into zhS/zlS.
        // D layout: col = ct*32 + rb, row = rtile*32 + (reg&3)+8*(reg>>2)+4*hi.
        #pragma unroll
        for (int ci = 0; ci < 2; ++ci) {
            const int ct = cpar + ci * 2;
            const int ccol = ct * 32 + rb;
            const float bvv = biasS[col0 + ccol];
            f32x16 zv = zacc[nc * 2 + ci];
            #pragma unroll
            for (int reg = 0; reg < 16; ++reg) {
                const int zrow = rtile * 32 + (reg & 3) + 8 * (reg >> 2) + 4 * hi;
                const float v = zv[reg] + bvv;
                Z[(row0 + zrow) * DIM + col0 + ccol] = v;
                _Float16 hh, ll; split_f32(v, hh, ll);
                zhS[zrow][ccol] = hh;
                zlS[zrow][ccol] = ll;
            }
        }
        __syncthreads();   // zhS/zlS ready (cb tile staged at prev sub-step)

        #pragma unroll
        for (int ks = 0; ks < 4; ++ks) {
            const int cur = ks & 1;
            const int nxt = cur ^ 1;
            if (!(nc == 3 && ks == 3)) {
                const int ncn = (ks == 3) ? nc + 1 : nc;
                const int ksn = (ks + 1) & 3;
                stage_tile(Ch + ncn * 128 + ksn * 32,
                           Cl + ncn * 128 + ksn * 32, nxt);
            }
            // z B-frags (z^T): lane = z-row rtile*32+rb, k = ks*32+k16+hi*8.
            const int zoff = ks * 32 + hi * 8;
            const int zr = rtile * 32 + rb;
            half8 zh0 = *(const half8*)&zhS[zr][zoff];
            half8 zl0 = *(const half8*)&zlS[zr][zoff];
            half8 zh1 = *(const half8*)&zhS[zr][zoff + 16];
            half8 zl1 = *(const half8*)&zlS[zr][zoff + 16];
            const char* bhp = (const char*)&BhS[cur][0][0];
            const char* blp = (const char*)&BlS[cur][0][0];
            #pragma unroll
            for (int ci = 0; ci < 2; ++ci) {
                const int brow = ci ? browB : browA;
                f32x16 acc = Sacc[ci];
                {   // khalf 0: A = cb frag, B = z frag
                    const int off = brow + ck0;
                    half8 ch = *(const half8*)(bhp + off);
                    half8 cl = *(const half8*)(blp + off);
                    acc = __builtin_amdgcn_mfma_f32_32x32x16_f16(ch, zh0, acc, 0, 0, 0);
                    acc = __builtin_amdgcn_mfma_f32_32x32x16_f16(ch, zl0, acc, 0, 0, 0);
                    acc = __builtin_amdgcn_mfma_f32_32x32x16_f16(cl, zh0, acc, 0, 0, 0);
                }
                {   // khalf 1
                    const int off = brow + (ck0 ^ 32);
                    half8 ch = *(const half8*)(bhp + off);
                    half8 cl = *(const half8*)(blp + off);
                    acc = __builtin_amdgcn_mfma_f32_32x32x16_f16(ch, zh1, acc, 0, 0, 0);
                    acc = __builtin_amdgcn_mfma_f32_32x32x16_f16(ch, zl1, acc, 0, 0, 0);
                    acc = __builtin_amdgcn_mfma_f32_32x32x16_f16(cl, zh1, acc, 0, 0, 0);
                }
                Sacc[ci] = acc;
            }
            __syncthreads();
        }
    }

    // Argmin: S^T D-layout -> lane owns z-row rtile*32+rb with codes
    // ct*32 + (reg&3)+8*(reg>>2)+4*hi for ct in {cpar, cpar+2}.
    float bv = __builtin_inff();
    int   bi = 0;
    #pragma unroll
    for (int ci = 0; ci < 2; ++ci) {
        const int ct = cpar + ci * 2;
        #pragma unroll
        for (int reg = 0; reg < 16; ++reg) {
            const int code = ct * 32 + (reg & 3) + 8 * (reg >> 2) + 4 * hi;
            const float v = fmaf(-2.f, Sacc[ci][reg], cnS[code]);
            if (v < bv || (v == bv && code < bi)) { bv = v; bi = code; }
        }
    }
    {   // combine with hi-partner (same z-row, other 32 codes of this wave)
        const float ov = __shfl_xor(bv, 32, 64);
        const int   oi = __shfl_xor(bi, 32, 64);
        if (ov < bv || (ov == bv && oi < bi)) { bv = ov; bi = oi; }
    }
    if (lane < 32) { wval[w][rb] = bv; widx[w][rb] = bi; }
    __syncthreads();
    // Cross-wave combine: row t served by waves {t>>5, (t>>5)+2}.
    if (tid < 64) {
        const int rt = tid >> 5, r = tid & 31;
        float v0 = wval[rt][r];     int i0 = widx[rt][r];
        float v1 = wval[rt + 2][r]; int i1 = widx[rt + 2][r];
        if (v1 < v0 || (v1 == v0 && i1 < i0)) { v0 = v1; i0 = i1; }
        amin[tid] = i0;
    }
    __syncthreads();

    // Gather: wave per row, 8 floats/lane, bitwise codebook copy to q1,q2.
    for (int r = w; r < 64; r += 4) {
        const int idx = amin[r];
        const float4* src = (const float4*)&cb[(size_t)idx * DIM];
        float4 v0 = src[lane * 2 + 0];
        float4 v1 = src[lane * 2 + 1];
        float4* d1 = (float4*)&q1[(row0 + r) * DIM];
        float4* d2 = (float4*)&q2[(row0 + r) * DIM];
        d1[lane * 2 + 0] = v0; d1[lane * 2 + 1] = v1;
        d2[lane * 2 + 0] = v0; d2[lane * 2 + 1] = v1;
    }
}

// ---------------------------------------------------------------------------
extern "C" void kernel_launch(void* const* d_in, const int* in_sizes, int n_in,
                              void* d_out, int out_size, void* d_ws, size_t ws_size,
                              hipStream_t stream) {
    const float* x    = (const float*)d_in[0];
    const float* Wenc = (const float*)d_in[1];
    const float* benc = (const float*)d_in[2];
    const float* cb   = (const float*)d_in[3];

    const int B = in_sizes[0] / DIM;             // 32768

    float* out = (float*)d_out;
    float* q1 = out;
    float* q2 = out + (size_t)B * DIM;
    float* z  = out + (size_t)2 * B * DIM;

    // ws carve (16B-aligned): cn | Wh | Wl | Ch | Cl  (~1.3 MB total)
    char* wsb = (char*)d_ws;
    float*    cn = (float*)wsb;                          // 512 B
    _Float16* Wh = (_Float16*)(wsb + 4096);              // 512 KB
    _Float16* Wl = (_Float16*)(wsb + 4096 + 524288);     // 512 KB
    _Float16* Ch = (_Float16*)(wsb + 4096 + 1048576);    // 128 KB
    _Float16* Cl = (_Float16*)(wsb + 4096 + 1179648);    // 128 KB

    presplit_kernel<<<320, 256, 0, stream>>>(Wenc, cb, Wh, Wl, Ch, Cl);
    code_norms_kernel<<<NCODES / 8, 256, 0, stream>>>(cb, cn);

    fused_kernel<<<B / 64, 256, 0, stream>>>(x, Wh, Wl, Ch, Cl, cb, benc, cn,
                                             z, q1, q2);
}

// Round 3
// 294.508 us; speedup vs baseline: 1.0173x; 1.0173x over previous
//
#include <hip/hip_runtime.h>
#include <cstdint>
#include <cstddef>

// x [8,4096,512] fp32, W_enc [512,512], b_enc [512], code_book [128,512].
// Outputs: q, q, z -> 3 x B*DIM fp32. B = 32768.
//
// Round-N+2: 32x32x16 MFMA K-outer structure (round-2) with the PROVEN LDS
// swizzle restored: chunk position p of row r holds global chunk
// p ^ ((r>>1)&3). Read of global chunk (2kh+hi) for row r is at byte
// ((hi ^ ((r>>1)&3)) * 16) ^ (kh*32) -- covers all 8 bank-quads per
// 8-lane phase (round-2's p^(r&3) covered only 4 -> 15.7M conflicts).
// zhS/zlS stride padded 132->136: S-phase z-frag read becomes
// quad = (zr + 4ks + hi) mod 8 -> conflict-free.

#define DIM     512
#define NCODES  128

typedef _Float16 half8  __attribute__((ext_vector_type(8)));
typedef _Float16 half4h __attribute__((ext_vector_type(4)));
typedef float    f32x4  __attribute__((ext_vector_type(4)));
typedef float    f32x16 __attribute__((ext_vector_type(16)));

__device__ __forceinline__ void load_lds16(const void* gptr, void* ldsptr) {
    __builtin_amdgcn_global_load_lds(
        (const __attribute__((address_space(1))) uint32_t*)(uintptr_t)gptr,
        (__attribute__((address_space(3))) uint32_t*)(uintptr_t)ldsptr,
        16, 0, 0);
}

__device__ __forceinline__ void split_f32(float v, _Float16& h, _Float16& l) {
    h = (_Float16)v;
    l = (_Float16)(v - (float)h);
}

// ---------------------------------------------------------------------------
// Kernel P: split W (512x512) and cb (128x512) into f16 hi/lo arrays in ws.
// ---------------------------------------------------------------------------
__global__ __launch_bounds__(256) void presplit_kernel(
        const float* __restrict__ W, const float* __restrict__ cb,
        _Float16* __restrict__ Wh, _Float16* __restrict__ Wl,
        _Float16* __restrict__ Ch, _Float16* __restrict__ Cl) {
    const int gid = blockIdx.x * 256 + threadIdx.x;
    const float* src; _Float16 *dh, *dl; size_t e;
    if (gid < 65536) { src = W;  dh = Wh; dl = Wl; e = (size_t)gid * 4; }
    else             { src = cb; dh = Ch; dl = Cl; e = (size_t)(gid - 65536) * 4; }
    float4 v = *(const float4*)&src[e];
    _Float16 h0, h1, h2, h3, l0, l1, l2, l3;
    split_f32(v.x, h0, l0); split_f32(v.y, h1, l1);
    split_f32(v.z, h2, l2); split_f32(v.w, h3, l3);
    *(half4h*)&dh[e] = half4h{h0, h1, h2, h3};
    *(half4h*)&dl[e] = half4h{l0, l1, l2, l3};
}

// ---------------------------------------------------------------------------
// Kernel 0: per-code squared norms (fp32). 16 blocks x 256 thr.
// ---------------------------------------------------------------------------
__global__ void code_norms_kernel(const float* __restrict__ cb,
                                  float* __restrict__ cn) {
    const int tid = threadIdx.x;
    const int g = tid >> 5, l = tid & 31;
    const int code = blockIdx.x * 8 + g;
    const float4* row = (const float4*)(cb + (size_t)code * DIM);
    float s = 0.f;
    #pragma unroll
    for (int i = 0; i < 4; ++i) {
        float4 v = row[l + 32 * i];
        s = fmaf(v.x, v.x, s); s = fmaf(v.y, v.y, s);
        s = fmaf(v.z, v.z, s); s = fmaf(v.w, v.w, s);
    }
    #pragma unroll
    for (int m = 16; m >= 1; m >>= 1) s += __shfl_xor(s, m, 64);
    if (l == 0) cn[code] = s;
}

// ---------------------------------------------------------------------------
// Fused kernel: 512 blocks x 64 rows, 256 thr (4 waves).
// Wave w: rtile = w&1 (rows rtile*32..+31), cpar = w>>1 (col-tiles
// {cpar, cpar+2} of each 128-col chunk => 256 cols/wave).
// 32x32x16 frag layouts: A/B lane l: row/col = l&31, k = (l>>5)*8 + 0..7.
// C/D lane l: col = l&31, row = (reg&3) + 8*(reg>>2) + 4*(l>>5).
// ---------------------------------------------------------------------------
__global__ __launch_bounds__(256, 2) void fused_kernel(
        const float* __restrict__ X, const _Float16* __restrict__ Wh,
        const _Float16* __restrict__ Wl, const _Float16* __restrict__ Ch,
        const _Float16* __restrict__ Cl, const float* __restrict__ cb,
        const float* __restrict__ bias, const float* __restrict__ cn,
        float* __restrict__ Z, float* __restrict__ q1,
        float* __restrict__ q2) {
    __shared__ _Float16 BhS[2][128][32];  // 16 KB (dbuf W tile, reused for cb)
    __shared__ _Float16 BlS[2][128][32];  // 16 KB
    __shared__ _Float16 zhS[64][136];     // 17 KB (stride 136: conflict-free)
    __shared__ _Float16 zlS[64][136];     // 17 KB
    __shared__ float    biasS[DIM];       // 2 KB
    __shared__ float    cnS[NCODES];
    __shared__ float    wval[4][32];
    __shared__ int      widx[4][32];
    __shared__ int      amin[64];

    const int tid  = threadIdx.x;
    const int lane = tid & 63;
    const int w    = tid >> 6;
    const int rb   = lane & 31;           // frag row/col within tile
    const int hi   = lane >> 5;           // k-half selector within frags
    const int rtile = w & 1;
    const int cpar  = w >> 1;
    const size_t row0 = (size_t)blockIdx.x * 64;
    const int wbase = tid & 192;          // wave-uniform thread base

    biasS[tid] = bias[tid];
    biasS[tid + 256] = bias[tid + 256];
    if (tid < NCODES) cnS[tid] = cn[tid];

    // Stage one 128x32-half tile (h and l) into LDS buffer with swizzle:
    // chunk position p of row r <- global chunk p ^ ((r>>1)&3).
    auto stage_tile = [&](const _Float16* __restrict__ srcH,
                          const _Float16* __restrict__ srcL,
                          int buf) {
        #pragma unroll
        for (int i = 0; i < 2; ++i) {
            const int slot = i * 256 + tid;
            const int r = slot >> 2, p = slot & 3;
            const int g = p ^ ((r >> 1) & 3);
            load_lds16(&srcH[(size_t)r * DIM + g * 8],
                       (char*)&BhS[buf][0][0] + (size_t)(i * 256 + wbase) * 16);
            load_lds16(&srcL[(size_t)r * DIM + g * 8],
                       (char*)&BlS[buf][0][0] + (size_t)(i * 256 + wbase) * 16);
        }
    };

    // B/A-frag LDS read offsets: row = ct*32 + rb (64 B/row); global chunk
    // (2kh+hi) of row r sits at byte (((2kh+hi) ^ ((r>>1)&3)) * 16)
    //  = ck0 ^ (kh*32) with ck0 = (hi ^ ((rb>>1)&3)) * 16.
    const int s2   = (rb >> 1) & 3;
    const int ck0  = (hi ^ s2) * 16;
    const int browA = (cpar * 32 + rb) * 64;        // ct = cpar
    const int browB = browA + 64 * 64;              // ct = cpar + 2

    // X A-frag: lane reads row rtile*32+rb, k = k0 + k16 + hi*8 + 0..7.
    const float* xptr = X + (row0 + rtile * 32 + rb) * DIM + hi * 8;

    f32x16 zacc[8] = {};   // [chunk nc * 2 + ci]

    // Prologue: stage (k0=0, nc=0) into buf0; prefetch first A groups.
    stage_tile(Wh, Wl, 0);
    f32x4 a00 = *(const f32x4*)(xptr + 0);
    f32x4 a01 = *(const f32x4*)(xptr + 4);
    f32x4 a10 = *(const f32x4*)(xptr + 16);
    f32x4 a11 = *(const f32x4*)(xptr + 20);
    __syncthreads();

    for (int k0i = 0; k0i < 16; ++k0i) {
        const int k0 = k0i * 32;
        // Split A groups (khalf0 from a00/a01, khalf1 from a10/a11).
        half8 ah0, al0, ah1, al1;
        {
            _Float16 h[8], l[8];
            split_f32(a00[0], h[0], l[0]); split_f32(a00[1], h[1], l[1]);
            split_f32(a00[2], h[2], l[2]); split_f32(a00[3], h[3], l[3]);
            split_f32(a01[0], h[4], l[4]); split_f32(a01[1], h[5], l[5]);
            split_f32(a01[2], h[6], l[6]); split_f32(a01[3], h[7], l[7]);
            ah0 = half8{h[0], h[1], h[2], h[3], h[4], h[5], h[6], h[7]};
            al0 = half8{l[0], l[1], l[2], l[3], l[4], l[5], l[6], l[7]};
            split_f32(a10[0], h[0], l[0]); split_f32(a10[1], h[1], l[1]);
            split_f32(a10[2], h[2], l[2]); split_f32(a10[3], h[3], l[3]);
            split_f32(a11[0], h[4], l[4]); split_f32(a11[1], h[5], l[5]);
            split_f32(a11[2], h[6], l[6]); split_f32(a11[3], h[7], l[7]);
            ah1 = half8{h[0], h[1], h[2], h[3], h[4], h[5], h[6], h[7]};
            al1 = half8{l[0], l[1], l[2], l[3], l[4], l[5], l[6], l[7]};
        }
        // Prefetch next k0's A groups.
        if (k0i < 15) {
            a00 = *(const f32x4*)(xptr + k0 + 32);
            a01 = *(const f32x4*)(xptr + k0 + 36);
            a10 = *(const f32x4*)(xptr + k0 + 48);
            a11 = *(const f32x4*)(xptr + k0 + 52);
        }

        #pragma unroll
        for (int nc = 0; nc < 4; ++nc) {
            const int s = k0i * 4 + nc;
            const int cur = s & 1;
            const int nxt = cur ^ 1;
            // Stage NEXT tile before computing current one.
            if (nc < 3 || k0i < 15) {
                const int ncn = (nc + 1) & 3;
                const int k0n = (nc == 3) ? (k0 + 32) : k0;
                stage_tile(Wh + (size_t)(ncn * 128) * DIM + k0n,
                           Wl + (size_t)(ncn * 128) * DIM + k0n, nxt);
            } else {
                // Last Z sub-step: prefetch first cb tile (nc=0, ks=0).
                stage_tile(Ch, Cl, nxt);
            }
            const char* bhp = (const char*)&BhS[cur][0][0];
            const char* blp = (const char*)&BlS[cur][0][0];
            #pragma unroll
            for (int ci = 0; ci < 2; ++ci) {
                const int brow = ci ? browB : browA;
                f32x16 acc = zacc[nc * 2 + ci];
                {   // khalf 0
                    const int off = brow + ck0;
                    half8 bh = *(const half8*)(bhp + off);
                    half8 bl = *(const half8*)(blp + off);
                    acc = __builtin_amdgcn_mfma_f32_32x32x16_f16(ah0, bh, acc, 0, 0, 0);
                    acc = __builtin_amdgcn_mfma_f32_32x32x16_f16(ah0, bl, acc, 0, 0, 0);
                    acc = __builtin_amdgcn_mfma_f32_32x32x16_f16(al0, bh, acc, 0, 0, 0);
                }
                {   // khalf 1
                    const int off = brow + (ck0 ^ 32);
                    half8 bh = *(const half8*)(bhp + off);
                    half8 bl = *(const half8*)(blp + off);
                    acc = __builtin_amdgcn_mfma_f32_32x32x16_f16(ah1, bh, acc, 0, 0, 0);
                    acc = __builtin_amdgcn_mfma_f32_32x32x16_f16(ah1, bl, acc, 0, 0, 0);
                    acc = __builtin_amdgcn_mfma_f32_32x32x16_f16(al1, bh, acc, 0, 0, 0);
                }
                zacc[nc * 2 + ci] = acc;
            }
            __syncthreads();
        }
    }

    // Tail: per nc chunk, epilogue + S^T accumulation (pipelined cb staging).
    f32x16 Sacc[2] = {};
    #pragma unroll
    for (int nc = 0; nc < 4; ++nc) {
        const int col0 = nc * 128;
        // Epilogue: +bias, store z to global, split into zhS/zlS.
        // D layout: col = ct*32 + rb, row = rtile*32 + (reg&3)+8*(reg>>2)+4*hi.
        #pragma unroll
        for (int ci = 0; ci < 2; ++ci) {
            const int ct = cpar + ci * 2;
            const int ccol = ct * 32 + rb;
            const float bvv = biasS[col0 + ccol];
            f32x16 zv = zacc[nc * 2 + ci];
            #pragma unroll
            for (int reg = 0; reg < 16; ++reg) {
                const int zrow = rtile * 32 + (reg & 3) + 8 * (reg >> 2) + 4 * hi;
                const float v = zv[reg] + bvv;
                Z[(row0 + zrow) * DIM + col0 + ccol] = v;
                _Float16 hh, ll; split_f32(v, hh, ll);
                zhS[zrow][ccol] = hh;
                zlS[zrow][ccol] = ll;
            }
        }
        __syncthreads();   // zhS/zlS ready (cb tile staged at prev sub-step)

        #pragma unroll
        for (int ks = 0; ks < 4; ++ks) {
            const int cur = ks & 1;
            const int nxt = cur ^ 1;
            if (!(nc == 3 && ks == 3)) {
                const int ncn = (ks == 3) ? nc + 1 : nc;
                const int ksn = (ks + 1) & 3;
                stage_tile(Ch + ncn * 128 + ksn * 32,
                           Cl + ncn * 128 + ksn * 32, nxt);
            }
            // z B-frags (z^T): lane = z-row rtile*32+rb, k = ks*32+k16+hi*8.
            const int zoff = ks * 32 + hi * 8;
            const int zr = rtile * 32 + rb;
            half8 zh0 = *(const half8*)&zhS[zr][zoff];
            half8 zl0 = *(const half8*)&zlS[zr][zoff];
            half8 zh1 = *(const half8*)&zhS[zr][zoff + 16];
            half8 zl1 = *(const half8*)&zlS[zr][zoff + 16];
            const char* bhp = (const char*)&BhS[cur][0][0];
            const char* blp = (const char*)&BlS[cur][0][0];
            #pragma unroll
            for (int ci = 0; ci < 2; ++ci) {
                const int brow = ci ? browB : browA;
                f32x16 acc = Sacc[ci];
                {   // khalf 0: A = cb frag, B = z frag
                    const int off = brow + ck0;
                    half8 ch = *(const half8*)(bhp + off);
                    half8 cl = *(const half8*)(blp + off);
                    acc = __builtin_amdgcn_mfma_f32_32x32x16_f16(ch, zh0, acc, 0, 0, 0);
                    acc = __builtin_amdgcn_mfma_f32_32x32x16_f16(ch, zl0, acc, 0, 0, 0);
                    acc = __builtin_amdgcn_mfma_f32_32x32x16_f16(cl, zh0, acc, 0, 0, 0);
                }
                {   // khalf 1
                    const int off = brow + (ck0 ^ 32);
                    half8 ch = *(const half8*)(bhp + off);
                    half8 cl = *(const half8*)(blp + off);
                    acc = __builtin_amdgcn_mfma_f32_32x32x16_f16(ch, zh1, acc, 0, 0, 0);
                    acc = __builtin_amdgcn_mfma_f32_32x32x16_f16(ch, zl1, acc, 0, 0, 0);
                    acc = __builtin_amdgcn_mfma_f32_32x32x16_f16(cl, zh1, acc, 0, 0, 0);
                }
                Sacc[ci] = acc;
            }
            __syncthreads();
        }
    }

    // Argmin: S^T D-layout -> lane owns z-row rtile*32+rb with codes
    // ct*32 + (reg&3)+8*(reg>>2)+4*hi for ct in {cpar, cpar+2}.
    float bv = __builtin_inff();
    int   bi = 0;
    #pragma unroll
    for (int ci = 0; ci < 2; ++ci) {
        const int ct = cpar + ci * 2;
        #pragma unroll
        for (int reg = 0; reg < 16; ++reg) {
            const int code = ct * 32 + (reg & 3) + 8 * (reg >> 2) + 4 * hi;
            const float v = fmaf(-2.f, Sacc[ci][reg], cnS[code]);
            if (v < bv || (v == bv && code < bi)) { bv = v; bi = code; }
        }
    }
    {   // combine with hi-partner (same z-row, other 32 codes of this wave)
        const float ov = __shfl_xor(bv, 32, 64);
        const int   oi = __shfl_xor(bi, 32, 64);
        if (ov < bv || (ov == bv && oi < bi)) { bv = ov; bi = oi; }
    }
    if (lane < 32) { wval[w][rb] = bv; widx[w][rb] = bi; }
    __syncthreads();
    // Cross-wave combine: row t served by waves {t>>5, (t>>5)+2}.
    if (tid < 64) {
        const int rt = tid >> 5, r = tid & 31;
        float v0 = wval[rt][r];     int i0 = widx[rt][r];
        float v1 = wval[rt + 2][r]; int i1 = widx[rt + 2][r];
        if (v1 < v0 || (v1 == v0 && i1 < i0)) { v0 = v1; i0 = i1; }
        amin[tid] = i0;
    }
    __syncthreads();

    // Gather: wave per row, 8 floats/lane, bitwise codebook copy to q1,q2.
    for (int r = w; r < 64; r += 4) {
        const int idx = amin[r];
        const float4* src = (const float4*)&cb[(size_t)idx * DIM];
        float4 v0 = src[lane * 2 + 0];
        float4 v1 = src[lane * 2 + 1];
        float4* d1 = (float4*)&q1[(row0 + r) * DIM];
        float4* d2 = (float4*)&q2[(row0 + r) * DIM];
        d1[lane * 2 + 0] = v0; d1[lane * 2 + 1] = v1;
        d2[lane * 2 + 0] = v0; d2[lane * 2 + 1] = v1;
    }
}

// ---------------------------------------------------------------------------
extern "C" void kernel_launch(void* const* d_in, const int* in_sizes, int n_in,
                              void* d_out, int out_size, void* d_ws, size_t ws_size,
                              hipStream_t stream) {
    const float* x    = (const float*)d_in[0];
    const float* Wenc = (const float*)d_in[1];
    const float* benc = (const float*)d_in[2];
    const float* cb   = (const float*)d_in[3];

    const int B = in_sizes[0] / DIM;             // 32768

    float* out = (float*)d_out;
    float* q1 = out;
    float* q2 = out + (size_t)B * DIM;
    float* z  = out + (size_t)2 * B * DIM;

    // ws carve (16B-aligned): cn | Wh | Wl | Ch | Cl  (~1.3 MB total)
    char* wsb = (char*)d_ws;
    float*    cn = (float*)wsb;                          // 512 B
    _Float16* Wh = (_Float16*)(wsb + 4096);              // 512 KB
    _Float16* Wl = (_Float16*)(wsb + 4096 + 524288);     // 512 KB
    _Float16* Ch = (_Float16*)(wsb + 4096 + 1048576);    // 128 KB
    _Float16* Cl = (_Float16*)(wsb + 4096 + 1179648);    // 128 KB

    presplit_kernel<<<320, 256, 0, stream>>>(Wenc, cb, Wh, Wl, Ch, Cl);
    code_norms_kernel<<<NCODES / 8, 256, 0, stream>>>(cb, cn);

    fused_kernel<<<B / 64, 256, 0, stream>>>(x, Wh, Wl, Ch, Cl, cb, benc, cn,
                                             z, q1, q2);
}